// Round 1
// baseline (321.891 us; speedup 1.0000x reference)
//
#include <hip/hip_runtime.h>
#include <hip/hip_bf16.h>

// Problem: B=4, S=2048, D=1024 (IN_F=OUT_F=1024)
// q = relu(x @ Wq^T + bq); k,v likewise; out = softmax(q k^T) v  (per batch)
//
// Strategy: bf16 MFMA (16x16x32) for all three GEMM stages, fp32 accumulate.
// ws layout: q(16MB) | k(16MB) | v(16MB) | vt(16MB) | logits(64MB fp32,
//            softmax overwrites in-place with bf16 probs, row stride kept).

#define SEQ 2048
#define DIM 1024
#define NB 4
#define MTOT (NB * SEQ)   // 8192

typedef __attribute__((ext_vector_type(8))) short frag_ab;
typedef __attribute__((ext_vector_type(4))) float frag_cd;

__device__ __forceinline__ ushort f2bf(float f) {
    union { float f; unsigned u; } x; x.f = f;
    unsigned r = x.u + 0x7fffu + ((x.u >> 16) & 1u);  // RNE
    return (ushort)(r >> 16);
}

// ---------------------------------------------------------------------------
// Kernel 1: C[m][n] = relu(sum_k x[m][k] * W[n][k] + b[n])  -> bf16
// x fp32 [8192,1024], W fp32 [1024,1024] (row-major over k: B^T layout)
// grid: (64, 8, 3); block 256
// ---------------------------------------------------------------------------
__global__ __launch_bounds__(256) void qkv_kernel(
    const float* __restrict__ x,
    const float* __restrict__ Wq, const float* __restrict__ bq,
    const float* __restrict__ Wk, const float* __restrict__ bk,
    const float* __restrict__ Wv, const float* __restrict__ bv,
    ushort* __restrict__ q, ushort* __restrict__ k, ushort* __restrict__ v)
{
    const float* W; const float* bias; ushort* out;
    if (blockIdx.z == 0)      { W = Wq; bias = bq; out = q; }
    else if (blockIdx.z == 1) { W = Wk; bias = bk; out = k; }
    else                      { W = Wv; bias = bv; out = v; }

    __shared__ ushort As[128][40];   // 128x32 bf16, pad to 40 (80B rows, 16B-aligned)
    __shared__ ushort Bs[128][40];

    const int tid  = threadIdx.x;
    const int wave = tid >> 6;
    const int lane = tid & 63;
    const int l16  = lane & 15;
    const int quad = lane >> 4;
    const int m0 = blockIdx.x * 128;
    const int n0 = blockIdx.y * 128;
    const int wm = (wave & 1) * 64;
    const int wn = (wave >> 1) * 64;

    const int sr = tid >> 3;        // 0..31
    const int sc = (tid & 7) * 4;   // 0,4,..,28

    frag_cd acc[4][4] = {};

    for (int k0 = 0; k0 < DIM; k0 += 32) {
        #pragma unroll
        for (int i = 0; i < 4; ++i) {
            int row = i * 32 + sr;
            float4 f = *(const float4*)&x[(size_t)(m0 + row) * DIM + k0 + sc];
            ushort4 u; u.x = f2bf(f.x); u.y = f2bf(f.y); u.z = f2bf(f.z); u.w = f2bf(f.w);
            *(ushort4*)&As[row][sc] = u;
        }
        #pragma unroll
        for (int i = 0; i < 4; ++i) {
            int row = i * 32 + sr;
            float4 f = *(const float4*)&W[(size_t)(n0 + row) * DIM + k0 + sc];
            ushort4 u; u.x = f2bf(f.x); u.y = f2bf(f.y); u.z = f2bf(f.z); u.w = f2bf(f.w);
            *(ushort4*)&Bs[row][sc] = u;
        }
        __syncthreads();
        frag_ab af[4], bfr[4];
        #pragma unroll
        for (int mi = 0; mi < 4; ++mi)
            af[mi] = *(const frag_ab*)&As[wm + mi * 16 + l16][quad * 8];
        #pragma unroll
        for (int ni = 0; ni < 4; ++ni)
            bfr[ni] = *(const frag_ab*)&Bs[wn + ni * 16 + l16][quad * 8];
        #pragma unroll
        for (int mi = 0; mi < 4; ++mi)
            #pragma unroll
            for (int ni = 0; ni < 4; ++ni)
                acc[mi][ni] = __builtin_amdgcn_mfma_f32_16x16x32_bf16(
                    af[mi], bfr[ni], acc[mi][ni], 0, 0, 0);
        __syncthreads();
    }

    #pragma unroll
    for (int ni = 0; ni < 4; ++ni) {
        int col = n0 + wn + ni * 16 + l16;
        float bb = bias[col];
        #pragma unroll
        for (int mi = 0; mi < 4; ++mi) {
            int rowb = m0 + wm + mi * 16 + quad * 4;
            #pragma unroll
            for (int r = 0; r < 4; ++r) {
                float val = acc[mi][ni][r] + bb;
                val = val > 0.0f ? val : 0.0f;
                out[(size_t)(rowb + r) * DIM + col] = f2bf(val);
            }
        }
    }
}

// ---------------------------------------------------------------------------
// Kernel 2: vt[bz][o][s] = v[bz][s][o]   (bf16, LDS-tiled 64x64 transpose)
// grid: (32, 16, 4); block 256
// ---------------------------------------------------------------------------
__global__ __launch_bounds__(256) void transpose_v(
    const ushort* __restrict__ v, ushort* __restrict__ vt)
{
    __shared__ ushort T[64][72];
    const int bz = blockIdx.z;
    const int s0 = blockIdx.x * 64;
    const int o0 = blockIdx.y * 64;
    const int t  = threadIdx.x;

    #pragma unroll
    for (int p = 0; p < 4; ++p) {
        int sl = p * 16 + (t >> 4);
        int o4 = (t & 15) * 4;
        ushort4 u = *(const ushort4*)&v[(size_t)(bz * SEQ + s0 + sl) * DIM + o0 + o4];
        *(ushort4*)&T[sl][o4] = u;
    }
    __syncthreads();
    #pragma unroll
    for (int p = 0; p < 4; ++p) {
        int ol = p * 16 + (t >> 4);
        int s4 = (t & 15) * 4;
        ushort4 u;
        u.x = T[s4 + 0][ol]; u.y = T[s4 + 1][ol];
        u.z = T[s4 + 2][ol]; u.w = T[s4 + 3][ol];
        *(ushort4*)&vt[(size_t)(bz * DIM + o0 + ol) * SEQ + s0 + s4] = u;
    }
}

// ---------------------------------------------------------------------------
// Kernel 3: logits[bz][i][j] = sum_d q[bz][i][d] * k[bz][j][d]   (fp32 out)
// grid: (16, 16, 4); block 256
// ---------------------------------------------------------------------------
__global__ __launch_bounds__(256) void qk_kernel(
    const ushort* __restrict__ q, const ushort* __restrict__ kk,
    float* __restrict__ logits)
{
    __shared__ ushort As[128][40];
    __shared__ ushort Bs[128][40];

    const int tid  = threadIdx.x;
    const int wave = tid >> 6;
    const int lane = tid & 63;
    const int l16  = lane & 15;
    const int quad = lane >> 4;
    const int bz = blockIdx.z;
    const int m0 = blockIdx.x * 128;
    const int n0 = blockIdx.y * 128;
    const int wm = (wave & 1) * 64;
    const int wn = (wave >> 1) * 64;
    const size_t base = (size_t)bz * SEQ;

    const int sr = tid >> 2;        // 0..63
    const int sc = (tid & 3) * 8;   // 0,8,16,24

    frag_cd acc[4][4] = {};

    for (int k0 = 0; k0 < DIM; k0 += 32) {
        #pragma unroll
        for (int i = 0; i < 2; ++i) {
            int row = i * 64 + sr;
            *(uint4*)&As[row][sc] =
                *(const uint4*)&q[(base + m0 + row) * DIM + k0 + sc];
            *(uint4*)&Bs[row][sc] =
                *(const uint4*)&kk[(base + n0 + row) * DIM + k0 + sc];
        }
        __syncthreads();
        frag_ab af[4], bfr[4];
        #pragma unroll
        for (int mi = 0; mi < 4; ++mi)
            af[mi] = *(const frag_ab*)&As[wm + mi * 16 + l16][quad * 8];
        #pragma unroll
        for (int ni = 0; ni < 4; ++ni)
            bfr[ni] = *(const frag_ab*)&Bs[wn + ni * 16 + l16][quad * 8];
        #pragma unroll
        for (int mi = 0; mi < 4; ++mi)
            #pragma unroll
            for (int ni = 0; ni < 4; ++ni)
                acc[mi][ni] = __builtin_amdgcn_mfma_f32_16x16x32_bf16(
                    af[mi], bfr[ni], acc[mi][ni], 0, 0, 0);
        __syncthreads();
    }

    #pragma unroll
    for (int mi = 0; mi < 4; ++mi) {
        int rowb = m0 + wm + mi * 16 + quad * 4;
        #pragma unroll
        for (int r = 0; r < 4; ++r) {
            #pragma unroll
            for (int ni = 0; ni < 4; ++ni) {
                int col = n0 + wn + ni * 16 + l16;
                logits[(base + rowb + r) * SEQ + col] = acc[mi][ni][r];
            }
        }
    }
}

// ---------------------------------------------------------------------------
// Kernel 4: row softmax over 2048 fp32, write bf16 probs in-place.
// grid: 8192; block 256
// ---------------------------------------------------------------------------
__global__ __launch_bounds__(256) void softmax_kernel(float* __restrict__ logits)
{
    float* p = logits + (size_t)blockIdx.x * SEQ;
    const int t = threadIdx.x;
    const int wave = t >> 6, lane = t & 63;

    float4 a = ((const float4*)p)[t];
    float4 b = ((const float4*)p)[t + 256];

    float m = fmaxf(fmaxf(fmaxf(a.x, a.y), fmaxf(a.z, a.w)),
                    fmaxf(fmaxf(b.x, b.y), fmaxf(b.z, b.w)));
    #pragma unroll
    for (int off = 32; off; off >>= 1) m = fmaxf(m, __shfl_down(m, off, 64));

    __shared__ float red[4];
    if (lane == 0) red[wave] = m;
    __syncthreads();
    m = fmaxf(fmaxf(red[0], red[1]), fmaxf(red[2], red[3]));

    a.x = __expf(a.x - m); a.y = __expf(a.y - m);
    a.z = __expf(a.z - m); a.w = __expf(a.w - m);
    b.x = __expf(b.x - m); b.y = __expf(b.y - m);
    b.z = __expf(b.z - m); b.w = __expf(b.w - m);

    float s = (a.x + a.y + a.z + a.w) + (b.x + b.y + b.z + b.w);
    #pragma unroll
    for (int off = 32; off; off >>= 1) s += __shfl_down(s, off, 64);
    __syncthreads();                 // red reuse + all global reads done
    if (lane == 0) red[wave] = s;
    __syncthreads();
    s = red[0] + red[1] + red[2] + red[3];
    float inv = 1.0f / s;

    ushort* o = (ushort*)p;
    ushort4 u0, u1;
    u0.x = f2bf(a.x * inv); u0.y = f2bf(a.y * inv);
    u0.z = f2bf(a.z * inv); u0.w = f2bf(a.w * inv);
    u1.x = f2bf(b.x * inv); u1.y = f2bf(b.y * inv);
    u1.z = f2bf(b.z * inv); u1.w = f2bf(b.w * inv);
    ((ushort4*)o)[t]       = u0;
    ((ushort4*)o)[t + 256] = u1;
}

// ---------------------------------------------------------------------------
// Kernel 5: out[bz][i][o] = sum_s P[bz][i][s] * vt[bz][o][s]   (fp32 out)
// P bf16 rows at stride 4096 ushorts (in-place over fp32 logits rows)
// grid: (16, 8, 4); block 256
// ---------------------------------------------------------------------------
__global__ __launch_bounds__(256) void pv_kernel(
    const ushort* __restrict__ probs, const ushort* __restrict__ vt,
    float* __restrict__ out)
{
    __shared__ ushort As[128][40];
    __shared__ ushort Bs[128][40];

    const int tid  = threadIdx.x;
    const int wave = tid >> 6;
    const int lane = tid & 63;
    const int l16  = lane & 15;
    const int quad = lane >> 4;
    const int bz = blockIdx.z;
    const int m0 = blockIdx.x * 128;
    const int n0 = blockIdx.y * 128;
    const int wm = (wave & 1) * 64;
    const int wn = (wave >> 1) * 64;

    const int sr = tid >> 2;        // 0..63
    const int sc = (tid & 3) * 8;   // 0,8,16,24

    frag_cd acc[4][4] = {};

    for (int k0 = 0; k0 < SEQ; k0 += 32) {
        #pragma unroll
        for (int i = 0; i < 2; ++i) {
            int row = i * 64 + sr;
            *(uint4*)&As[row][sc] =
                *(const uint4*)&probs[((size_t)(bz * SEQ + m0 + row)) * 4096 + k0 + sc];
            *(uint4*)&Bs[row][sc] =
                *(const uint4*)&vt[((size_t)(bz * DIM + n0 + row)) * SEQ + k0 + sc];
        }
        __syncthreads();
        frag_ab af[4], bfr[4];
        #pragma unroll
        for (int mi = 0; mi < 4; ++mi)
            af[mi] = *(const frag_ab*)&As[wm + mi * 16 + l16][quad * 8];
        #pragma unroll
        for (int ni = 0; ni < 4; ++ni)
            bfr[ni] = *(const frag_ab*)&Bs[wn + ni * 16 + l16][quad * 8];
        #pragma unroll
        for (int mi = 0; mi < 4; ++mi)
            #pragma unroll
            for (int ni = 0; ni < 4; ++ni)
                acc[mi][ni] = __builtin_amdgcn_mfma_f32_16x16x32_bf16(
                    af[mi], bfr[ni], acc[mi][ni], 0, 0, 0);
        __syncthreads();
    }

    #pragma unroll
    for (int mi = 0; mi < 4; ++mi) {
        int rowb = m0 + wm + mi * 16 + quad * 4;
        #pragma unroll
        for (int r = 0; r < 4; ++r) {
            #pragma unroll
            for (int ni = 0; ni < 4; ++ni) {
                int col = n0 + wn + ni * 16 + l16;
                out[((size_t)(bz * SEQ + rowb + r)) * DIM + col] = acc[mi][ni][r];
            }
        }
    }
}

// ---------------------------------------------------------------------------
extern "C" void kernel_launch(void* const* d_in, const int* in_sizes, int n_in,
                              void* d_out, int out_size, void* d_ws, size_t ws_size,
                              hipStream_t stream)
{
    const float* x  = (const float*)d_in[0];
    const float* Wq = (const float*)d_in[1];
    const float* bq = (const float*)d_in[2];
    const float* Wk = (const float*)d_in[3];
    const float* bk = (const float*)d_in[4];
    const float* Wv = (const float*)d_in[5];
    const float* bv = (const float*)d_in[6];
    float* out = (float*)d_out;

    ushort* q  = (ushort*)d_ws;                      // 16 MB
    ushort* kk = q  + (size_t)MTOT * DIM;            // 16 MB
    ushort* v  = kk + (size_t)MTOT * DIM;            // 16 MB
    ushort* vt = v  + (size_t)MTOT * DIM;            // 16 MB
    float* logits = (float*)(vt + (size_t)MTOT * DIM);  // 64 MB

    qkv_kernel<<<dim3(MTOT / 128, DIM / 128, 3), 256, 0, stream>>>(
        x, Wq, bq, Wk, bk, Wv, bv, q, kk, v);
    transpose_v<<<dim3(SEQ / 64, DIM / 64, NB), 256, 0, stream>>>(v, vt);
    qk_kernel<<<dim3(SEQ / 128, SEQ / 128, NB), 256, 0, stream>>>(q, kk, logits);
    softmax_kernel<<<NB * SEQ, 256, 0, stream>>>(logits);
    pv_kernel<<<dim3(SEQ / 128, DIM / 128, NB), 256, 0, stream>>>(
        (const ushort*)logits, vt, out);
}

// Round 3
// 285.986 us; speedup vs baseline: 1.1255x; 1.1255x over previous
//
#include <hip/hip_runtime.h>
#include <hip/hip_bf16.h>

// B=4, S=2048, D=1024. q=relu(x Wq^T + bq) etc; out = softmax(q k^T) v.
// R3: same as R2 with pointer-arithmetic precedence fix in kernel_launch.
// Pre-convert fp32->bf16, m97-style GEMMs with global_load_lds(16B) +
// XOR-swizzled unpadded LDS tiles (2-way bank aliasing = free).
//
// ws layout (128 MB):
//   [0,16)   q bf16           [16,32) k bf16
//   [32,48)  v bf16           [48,64) vt bf16
//   [64,128) logits fp32 (softmax overwrites rows in-place with bf16 probs)
//   xb bf16 aliases [64,80), Wb bf16 aliases [80,86) -- consumed before qk
//   writes logits (stream-ordered).

#define SEQ 2048
#define DIM 1024
#define NB 4
#define MTOT (NB * SEQ)   // 8192

typedef __attribute__((ext_vector_type(8))) short frag_ab;
typedef __attribute__((ext_vector_type(4))) float frag_cd;

__device__ __forceinline__ ushort f2bf(float f) {
    union { float f; unsigned u; } x; x.f = f;
    unsigned r = x.u + 0x7fffu + ((x.u >> 16) & 1u);  // RNE
    return (ushort)(r >> 16);
}

typedef __attribute__((address_space(1))) const unsigned int guint;
typedef __attribute__((address_space(3))) unsigned int luint;

__device__ __forceinline__ void gld_lds16(const void* g, void* l) {
    __builtin_amdgcn_global_load_lds((guint*)g, (luint*)l, 16, 0, 0);
}

// ---------------------------------------------------------------------------
// Shared 128x128-tile bf16 MFMA mainloop. A,B pre-offset to tile row 0.
// lda/ldb in bf16 elems (multiples of 8). LDS tiles 128x32 unpadded,
// chunk-swizzled: global 16B-chunk cg of row r lives at chunk cg^((r>>1)&3).
// ---------------------------------------------------------------------------
__device__ __forceinline__ void gemm_tiles(
    const ushort* __restrict__ A, size_t lda,
    const ushort* __restrict__ B, size_t ldb, int K,
    ushort* As, ushort* Bs, frag_cd (&acc)[4][4])
{
    const int tid  = threadIdx.x;
    const int wave = tid >> 6;
    const int lane = tid & 63;
    const int l16  = lane & 15;
    const int quad = lane >> 4;
    const int sr = wave * 16 + (lane >> 2);   // staging row (within 64-row half)
    const int sc = lane & 3;                  // staging 16B-chunk slot

    for (int k0 = 0; k0 < K; k0 += 32) {
        #pragma unroll
        for (int j = 0; j < 2; ++j) {
            int row = j * 64 + sr;
            int cg  = sc ^ ((row >> 1) & 3);          // swizzled source chunk
            ushort* la = As + (j * 64 + wave * 16) * 32;  // wave-uniform base
            ushort* lb = Bs + (j * 64 + wave * 16) * 32;
            gld_lds16(A + (size_t)row * lda + k0 + cg * 8, la);
            gld_lds16(B + (size_t)row * ldb + k0 + cg * 8, lb);
        }
        __syncthreads();
        frag_ab af[4], bfr[4];
        const int wm = (wave & 1) * 64;
        const int wn = (wave >> 1) * 64;
        #pragma unroll
        for (int mi = 0; mi < 4; ++mi) {
            int row = wm + mi * 16 + l16;
            int s = quad ^ ((row >> 1) & 3);
            af[mi] = *(const frag_ab*)&As[row * 32 + s * 8];
        }
        #pragma unroll
        for (int ni = 0; ni < 4; ++ni) {
            int row = wn + ni * 16 + l16;
            int s = quad ^ ((row >> 1) & 3);
            bfr[ni] = *(const frag_ab*)&Bs[row * 32 + s * 8];
        }
        #pragma unroll
        for (int mi = 0; mi < 4; ++mi)
            #pragma unroll
            for (int ni = 0; ni < 4; ++ni)
                acc[mi][ni] = __builtin_amdgcn_mfma_f32_16x16x32_bf16(
                    af[mi], bfr[ni], acc[mi][ni], 0, 0, 0);
        __syncthreads();
    }
}

// ---------------------------------------------------------------------------
// fp32 -> bf16 converters (memory-bound)
// ---------------------------------------------------------------------------
__global__ __launch_bounds__(256) void cvt_x_kernel(
    const float* __restrict__ src, ushort* __restrict__ dst)
{
    size_t i = (size_t)blockIdx.x * 256 + threadIdx.x;   // i indexes float4
    float4 f = ((const float4*)src)[i];
    ushort4 u; u.x = f2bf(f.x); u.y = f2bf(f.y); u.z = f2bf(f.z); u.w = f2bf(f.w);
    ((ushort4*)dst)[i] = u;
}

__global__ __launch_bounds__(256) void cvt_w_kernel(
    const float* __restrict__ Wq, const float* __restrict__ Wk,
    const float* __restrict__ Wv, ushort* __restrict__ dst)
{
    const float* src = blockIdx.y == 0 ? Wq : (blockIdx.y == 1 ? Wk : Wv);
    ushort* d = dst + (size_t)blockIdx.y * DIM * DIM;
    size_t i = (size_t)blockIdx.x * 256 + threadIdx.x;
    float4 f = ((const float4*)src)[i];
    ushort4 u; u.x = f2bf(f.x); u.y = f2bf(f.y); u.z = f2bf(f.z); u.w = f2bf(f.w);
    ((ushort4*)d)[i] = u;
}

// ---------------------------------------------------------------------------
// Kernel 1: q/k/v = relu(x W^T + b) -> bf16.  grid (64, 8, 3), block 256
// ---------------------------------------------------------------------------
__global__ __launch_bounds__(256) void qkv_kernel(
    const ushort* __restrict__ xb, const ushort* __restrict__ Wb,
    const float* __restrict__ bq, const float* __restrict__ bk,
    const float* __restrict__ bv,
    ushort* __restrict__ q, ushort* __restrict__ k, ushort* __restrict__ v)
{
    const float* bias; ushort* out;
    if (blockIdx.z == 0)      { bias = bq; out = q; }
    else if (blockIdx.z == 1) { bias = bk; out = k; }
    else                      { bias = bv; out = v; }
    const ushort* W = Wb + (size_t)blockIdx.z * DIM * DIM;

    __shared__ ushort As[128 * 32];
    __shared__ ushort Bs[128 * 32];

    const int tid  = threadIdx.x;
    const int wave = tid >> 6;
    const int lane = tid & 63;
    const int l16  = lane & 15;
    const int quad = lane >> 4;
    const int m0 = blockIdx.x * 128;
    const int n0 = blockIdx.y * 128;
    const int wm = (wave & 1) * 64;
    const int wn = (wave >> 1) * 64;

    frag_cd acc[4][4] = {};
    gemm_tiles(xb + (size_t)m0 * DIM, DIM, W + (size_t)n0 * DIM, DIM, DIM,
               As, Bs, acc);

    #pragma unroll
    for (int ni = 0; ni < 4; ++ni) {
        int col = n0 + wn + ni * 16 + l16;
        float bb = bias[col];
        #pragma unroll
        for (int mi = 0; mi < 4; ++mi) {
            int rowb = m0 + wm + mi * 16 + quad * 4;
            #pragma unroll
            for (int r = 0; r < 4; ++r) {
                float val = acc[mi][ni][r] + bb;
                val = val > 0.0f ? val : 0.0f;
                out[(size_t)(rowb + r) * DIM + col] = f2bf(val);
            }
        }
    }
}

// ---------------------------------------------------------------------------
// Kernel 2: vt[bz][o][s] = v[bz][s][o]  (bf16 64x64 LDS transpose)
// ---------------------------------------------------------------------------
__global__ __launch_bounds__(256) void transpose_v(
    const ushort* __restrict__ v, ushort* __restrict__ vt)
{
    __shared__ ushort T[64][72];
    const int bz = blockIdx.z;
    const int s0 = blockIdx.x * 64;
    const int o0 = blockIdx.y * 64;
    const int t  = threadIdx.x;

    #pragma unroll
    for (int p = 0; p < 4; ++p) {
        int sl = p * 16 + (t >> 4);
        int o4 = (t & 15) * 4;
        ushort4 u = *(const ushort4*)&v[(size_t)(bz * SEQ + s0 + sl) * DIM + o0 + o4];
        *(ushort4*)&T[sl][o4] = u;
    }
    __syncthreads();
    #pragma unroll
    for (int p = 0; p < 4; ++p) {
        int ol = p * 16 + (t >> 4);
        int s4 = (t & 15) * 4;
        ushort4 u;
        u.x = T[s4 + 0][ol]; u.y = T[s4 + 1][ol];
        u.z = T[s4 + 2][ol]; u.w = T[s4 + 3][ol];
        *(ushort4*)&vt[(size_t)(bz * DIM + o0 + ol) * SEQ + s0 + s4] = u;
    }
}

// ---------------------------------------------------------------------------
// Kernel 3: logits = q k^T (fp32).  grid (16,16,4)
// ---------------------------------------------------------------------------
__global__ __launch_bounds__(256) void qk_kernel(
    const ushort* __restrict__ q, const ushort* __restrict__ kk,
    float* __restrict__ logits)
{
    __shared__ ushort As[128 * 32];
    __shared__ ushort Bs[128 * 32];

    const int tid  = threadIdx.x;
    const int wave = tid >> 6;
    const int lane = tid & 63;
    const int l16  = lane & 15;
    const int quad = lane >> 4;
    const int bz = blockIdx.z;
    const int m0 = blockIdx.x * 128;
    const int n0 = blockIdx.y * 128;
    const int wm = (wave & 1) * 64;
    const int wn = (wave >> 1) * 64;
    const size_t base = (size_t)bz * SEQ;

    frag_cd acc[4][4] = {};
    gemm_tiles(q + (base + m0) * DIM, DIM, kk + (base + n0) * DIM, DIM, DIM,
               As, Bs, acc);

    #pragma unroll
    for (int mi = 0; mi < 4; ++mi) {
        int rowb = m0 + wm + mi * 16 + quad * 4;
        #pragma unroll
        for (int r = 0; r < 4; ++r)
            #pragma unroll
            for (int ni = 0; ni < 4; ++ni) {
                int col = n0 + wn + ni * 16 + l16;
                logits[(base + rowb + r) * SEQ + col] = acc[mi][ni][r];
            }
    }
}

// ---------------------------------------------------------------------------
// Kernel 4: row softmax over 2048 fp32, write bf16 probs in-place.
// ---------------------------------------------------------------------------
__global__ __launch_bounds__(256) void softmax_kernel(float* __restrict__ logits)
{
    float* p = logits + (size_t)blockIdx.x * SEQ;
    const int t = threadIdx.x;
    const int wave = t >> 6, lane = t & 63;

    float4 a = ((const float4*)p)[t];
    float4 b = ((const float4*)p)[t + 256];

    float m = fmaxf(fmaxf(fmaxf(a.x, a.y), fmaxf(a.z, a.w)),
                    fmaxf(fmaxf(b.x, b.y), fmaxf(b.z, b.w)));
    #pragma unroll
    for (int off = 32; off; off >>= 1) m = fmaxf(m, __shfl_down(m, off, 64));

    __shared__ float red[4];
    if (lane == 0) red[wave] = m;
    __syncthreads();
    m = fmaxf(fmaxf(red[0], red[1]), fmaxf(red[2], red[3]));

    a.x = __expf(a.x - m); a.y = __expf(a.y - m);
    a.z = __expf(a.z - m); a.w = __expf(a.w - m);
    b.x = __expf(b.x - m); b.y = __expf(b.y - m);
    b.z = __expf(b.z - m); b.w = __expf(b.w - m);

    float s = (a.x + a.y + a.z + a.w) + (b.x + b.y + b.z + b.w);
    #pragma unroll
    for (int off = 32; off; off >>= 1) s += __shfl_down(s, off, 64);
    __syncthreads();
    if (lane == 0) red[wave] = s;
    __syncthreads();
    s = red[0] + red[1] + red[2] + red[3];
    float inv = 1.0f / s;

    ushort* o = (ushort*)p;
    ushort4 u0, u1;
    u0.x = f2bf(a.x * inv); u0.y = f2bf(a.y * inv);
    u0.z = f2bf(a.z * inv); u0.w = f2bf(a.w * inv);
    u1.x = f2bf(b.x * inv); u1.y = f2bf(b.y * inv);
    u1.z = f2bf(b.z * inv); u1.w = f2bf(b.w * inv);
    ((ushort4*)o)[t]       = u0;
    ((ushort4*)o)[t + 256] = u1;
}

// ---------------------------------------------------------------------------
// Kernel 5: out = P vt^T (fp32). P rows stride 4096 ushorts. grid (16,8,4)
// ---------------------------------------------------------------------------
__global__ __launch_bounds__(256) void pv_kernel(
    const ushort* __restrict__ probs, const ushort* __restrict__ vt,
    float* __restrict__ out)
{
    __shared__ ushort As[128 * 32];
    __shared__ ushort Bs[128 * 32];

    const int tid  = threadIdx.x;
    const int wave = tid >> 6;
    const int lane = tid & 63;
    const int l16  = lane & 15;
    const int quad = lane >> 4;
    const int bz = blockIdx.z;
    const int m0 = blockIdx.x * 128;
    const int n0 = blockIdx.y * 128;
    const int wm = (wave & 1) * 64;
    const int wn = (wave >> 1) * 64;

    frag_cd acc[4][4] = {};
    gemm_tiles(probs + ((size_t)(bz * SEQ + m0)) * 4096, 4096,
               vt + ((size_t)(bz * DIM + n0)) * SEQ, SEQ, SEQ,
               As, Bs, acc);

    #pragma unroll
    for (int mi = 0; mi < 4; ++mi) {
        int rowb = m0 + wm + mi * 16 + quad * 4;
        #pragma unroll
        for (int r = 0; r < 4; ++r)
            #pragma unroll
            for (int ni = 0; ni < 4; ++ni) {
                int col = n0 + wn + ni * 16 + l16;
                out[((size_t)(bz * SEQ + rowb + r)) * DIM + col] = acc[mi][ni][r];
            }
    }
}

// ---------------------------------------------------------------------------
extern "C" void kernel_launch(void* const* d_in, const int* in_sizes, int n_in,
                              void* d_out, int out_size, void* d_ws, size_t ws_size,
                              hipStream_t stream)
{
    const float* x  = (const float*)d_in[0];
    const float* Wq = (const float*)d_in[1];
    const float* bq = (const float*)d_in[2];
    const float* Wk = (const float*)d_in[3];
    const float* bk = (const float*)d_in[4];
    const float* Wv = (const float*)d_in[5];
    const float* bv = (const float*)d_in[6];
    float* out = (float*)d_out;

    char* ws = (char*)d_ws;
    ushort* q      = (ushort*)(ws);                           // 16 MB
    ushort* kk     = (ushort*)(ws + ((size_t)16 << 20));      // 16 MB
    ushort* v      = (ushort*)(ws + ((size_t)32 << 20));      // 16 MB
    ushort* vt     = (ushort*)(ws + ((size_t)48 << 20));      // 16 MB
    float*  logits = (float*) (ws + ((size_t)64 << 20));      // 64 MB
    ushort* xb     = (ushort*)(ws + ((size_t)64 << 20));      // aliases logits
    ushort* Wb     = (ushort*)(ws + ((size_t)80 << 20));      // aliases logits

    // fp32 -> bf16 (xb: 8M elems -> 2M float4; W: 1M elems -> 256K float4 each)
    cvt_x_kernel<<<dim3(MTOT * DIM / 4 / 256), 256, 0, stream>>>(x, xb);
    cvt_w_kernel<<<dim3(DIM * DIM / 4 / 256, 3), 256, 0, stream>>>(Wq, Wk, Wv, Wb);

    qkv_kernel<<<dim3(MTOT / 128, DIM / 128, 3), 256, 0, stream>>>(
        xb, Wb, bq, bk, bv, q, kk, v);
    transpose_v<<<dim3(SEQ / 64, DIM / 64, NB), 256, 0, stream>>>(v, vt);
    qk_kernel<<<dim3(SEQ / 128, SEQ / 128, NB), 256, 0, stream>>>(q, kk, logits);
    softmax_kernel<<<NB * SEQ, 256, 0, stream>>>(logits);
    pv_kernel<<<dim3(SEQ / 128, DIM / 128, NB), 256, 0, stream>>>(
        (const ushort*)logits, vt, out);
}

// Round 4
// 276.649 us; speedup vs baseline: 1.1635x; 1.0337x over previous
//
#include <hip/hip_runtime.h>
#include <hip/hip_bf16.h>

// B=4, S=2048, D=1024. q=relu(x Wq^T + bq) etc; out = softmax(q k^T) v.
// R4: switch GEMM mainloop to v_mfma_f32_32x32x16_bf16 (2382 vs 2075 TF
// ubench, same staging), merge cvt kernels. Staging/swizzle unchanged from
// R3 (global_load_lds 16B, XOR chunk swizzle, 0 conflicts measured).
//
// ws layout (128 MB):
//   [0,16)   q bf16           [16,32) k bf16
//   [32,48)  v bf16           [48,64) vt bf16
//   [64,128) logits fp32 (softmax overwrites rows in-place with bf16 probs)
//   xb bf16 aliases [64,80), Wb bf16 aliases [80,86) -- consumed by qkv
//   before qk writes logits (stream-ordered).

#define SEQ 2048
#define DIM 1024
#define NB 4
#define MTOT (NB * SEQ)   // 8192

typedef __attribute__((ext_vector_type(8))) short frag_ab;
typedef __attribute__((ext_vector_type(16))) float frag_c16;

__device__ __forceinline__ ushort f2bf(float f) {
    union { float f; unsigned u; } x; x.f = f;
    unsigned r = x.u + 0x7fffu + ((x.u >> 16) & 1u);  // RNE
    return (ushort)(r >> 16);
}

typedef __attribute__((address_space(1))) const unsigned int guint;
typedef __attribute__((address_space(3))) unsigned int luint;

__device__ __forceinline__ void gld_lds16(const void* g, void* l) {
    __builtin_amdgcn_global_load_lds((guint*)g, (luint*)l, 16, 0, 0);
}

// ---------------------------------------------------------------------------
// 128x128-tile bf16 MFMA mainloop, 32x32x16 shape. A,B pre-offset to tile
// row 0, K-contiguous (B^T convention), lda/ldb multiples of 8.
// LDS tiles 128x32 unpadded; global 16B-chunk cg of row r stored at physical
// chunk cg ^ ((r>>1)&3). Wave w owns the 64x64 subtile (wm,wn), split 2x2
// into 32x32 MFMA tiles.
// ---------------------------------------------------------------------------
__device__ __forceinline__ void gemm_tiles(
    const ushort* __restrict__ A, size_t lda,
    const ushort* __restrict__ B, size_t ldb, int K,
    ushort* As, ushort* Bs, frag_c16 (&acc)[2][2])
{
    const int tid  = threadIdx.x;
    const int wave = tid >> 6;
    const int lane = tid & 63;
    const int l32  = lane & 31;
    const int half = lane >> 5;
    const int sr = wave * 16 + (lane >> 2);   // staging row (within 64-row half)
    const int sc = lane & 3;                  // staging physical chunk slot
    const int wm = (wave & 1) * 64;
    const int wn = (wave >> 1) * 64;

    for (int k0 = 0; k0 < K; k0 += 32) {
        #pragma unroll
        for (int j = 0; j < 2; ++j) {
            int row = j * 64 + sr;
            int cg  = sc ^ ((row >> 1) & 3);          // swizzled source chunk
            ushort* la = As + (j * 64 + wave * 16) * 32;  // wave-uniform base
            ushort* lb = Bs + (j * 64 + wave * 16) * 32;
            gld_lds16(A + (size_t)row * lda + k0 + cg * 8, la);
            gld_lds16(B + (size_t)row * ldb + k0 + cg * 8, lb);
        }
        __syncthreads();
        frag_ab af[2][2], bfr[2][2];
        #pragma unroll
        for (int mi = 0; mi < 2; ++mi) {
            int row = wm + mi * 32 + l32;
            int sw = (row >> 1) & 3;
            #pragma unroll
            for (int h = 0; h < 2; ++h) {
                int c = (h * 2 + half) ^ sw;
                af[mi][h] = *(const frag_ab*)&As[row * 32 + c * 8];
            }
        }
        #pragma unroll
        for (int ni = 0; ni < 2; ++ni) {
            int row = wn + ni * 32 + l32;
            int sw = (row >> 1) & 3;
            #pragma unroll
            for (int h = 0; h < 2; ++h) {
                int c = (h * 2 + half) ^ sw;
                bfr[ni][h] = *(const frag_ab*)&Bs[row * 32 + c * 8];
            }
        }
        #pragma unroll
        for (int h = 0; h < 2; ++h)
            #pragma unroll
            for (int mi = 0; mi < 2; ++mi)
                #pragma unroll
                for (int ni = 0; ni < 2; ++ni)
                    acc[mi][ni] = __builtin_amdgcn_mfma_f32_32x32x16_bf16(
                        af[mi][h], bfr[ni][h], acc[mi][ni], 0, 0, 0);
        __syncthreads();
    }
}

// C/D layout (32x32): col = lane&31, row = (reg&3) + 8*(reg>>2) + 4*(lane>>5)

// ---------------------------------------------------------------------------
// fp32 -> bf16 converter, x + 3 weights in one launch (memory-bound)
// ---------------------------------------------------------------------------
#define NX4 (MTOT * DIM / 4)          // 2M float4 for x
#define NW4 (DIM * DIM / 4)           // 256K float4 per W
__global__ __launch_bounds__(256) void cvt_kernel(
    const float* __restrict__ x,
    const float* __restrict__ Wq, const float* __restrict__ Wk,
    const float* __restrict__ Wv,
    ushort* __restrict__ xb, ushort* __restrict__ Wb)
{
    size_t i = (size_t)blockIdx.x * 256 + threadIdx.x;
    const float* src; ushort* dst; size_t idx;
    if (i < NX4) { src = x; dst = xb; idx = i; }
    else {
        size_t j = i - NX4;
        int w = (int)(j >> 18);               // j / NW4
        idx = j & (NW4 - 1);
        src = w == 0 ? Wq : (w == 1 ? Wk : Wv);
        dst = Wb + (size_t)w * DIM * DIM;
    }
    float4 f = ((const float4*)src)[idx];
    ushort4 u; u.x = f2bf(f.x); u.y = f2bf(f.y); u.z = f2bf(f.z); u.w = f2bf(f.w);
    ((ushort4*)dst)[idx] = u;
}

// ---------------------------------------------------------------------------
// Kernel 1: q/k/v = relu(x W^T + b) -> bf16.  grid (64, 8, 3), block 256
// ---------------------------------------------------------------------------
__global__ __launch_bounds__(256) void qkv_kernel(
    const ushort* __restrict__ xb, const ushort* __restrict__ Wb,
    const float* __restrict__ bq, const float* __restrict__ bk,
    const float* __restrict__ bv,
    ushort* __restrict__ q, ushort* __restrict__ k, ushort* __restrict__ v)
{
    const float* bias; ushort* out;
    if (blockIdx.z == 0)      { bias = bq; out = q; }
    else if (blockIdx.z == 1) { bias = bk; out = k; }
    else                      { bias = bv; out = v; }
    const ushort* W = Wb + (size_t)blockIdx.z * DIM * DIM;

    __shared__ ushort As[128 * 32];
    __shared__ ushort Bs[128 * 32];

    const int tid  = threadIdx.x;
    const int wave = tid >> 6;
    const int lane = tid & 63;
    const int l32  = lane & 31;
    const int half = lane >> 5;
    const int m0 = blockIdx.x * 128;
    const int n0 = blockIdx.y * 128;
    const int wm = (wave & 1) * 64;
    const int wn = (wave >> 1) * 64;

    frag_c16 acc[2][2] = {};
    gemm_tiles(xb + (size_t)m0 * DIM, DIM, W + (size_t)n0 * DIM, DIM, DIM,
               As, Bs, acc);

    #pragma unroll
    for (int ni = 0; ni < 2; ++ni) {
        int col = n0 + wn + ni * 32 + l32;
        float bb = bias[col];
        #pragma unroll
        for (int mi = 0; mi < 2; ++mi)
            #pragma unroll
            for (int r = 0; r < 16; ++r) {
                int row = m0 + wm + mi * 32 + (r & 3) + 8 * (r >> 2) + 4 * half;
                float val = acc[mi][ni][r] + bb;
                val = val > 0.0f ? val : 0.0f;
                out[(size_t)row * DIM + col] = f2bf(val);
            }
    }
}

// ---------------------------------------------------------------------------
// Kernel 2: vt[bz][o][s] = v[bz][s][o]  (bf16 64x64 LDS transpose)
// ---------------------------------------------------------------------------
__global__ __launch_bounds__(256) void transpose_v(
    const ushort* __restrict__ v, ushort* __restrict__ vt)
{
    __shared__ ushort T[64][72];
    const int bz = blockIdx.z;
    const int s0 = blockIdx.x * 64;
    const int o0 = blockIdx.y * 64;
    const int t  = threadIdx.x;

    #pragma unroll
    for (int p = 0; p < 4; ++p) {
        int sl = p * 16 + (t >> 4);
        int o4 = (t & 15) * 4;
        ushort4 u = *(const ushort4*)&v[(size_t)(bz * SEQ + s0 + sl) * DIM + o0 + o4];
        *(ushort4*)&T[sl][o4] = u;
    }
    __syncthreads();
    #pragma unroll
    for (int p = 0; p < 4; ++p) {
        int ol = p * 16 + (t >> 4);
        int s4 = (t & 15) * 4;
        ushort4 u;
        u.x = T[s4 + 0][ol]; u.y = T[s4 + 1][ol];
        u.z = T[s4 + 2][ol]; u.w = T[s4 + 3][ol];
        *(ushort4*)&vt[(size_t)(bz * DIM + o0 + ol) * SEQ + s0 + s4] = u;
    }
}

// ---------------------------------------------------------------------------
// Kernel 3: logits = q k^T (fp32).  grid (16,16,4)
// ---------------------------------------------------------------------------
__global__ __launch_bounds__(256) void qk_kernel(
    const ushort* __restrict__ q, const ushort* __restrict__ kk,
    float* __restrict__ logits)
{
    __shared__ ushort As[128 * 32];
    __shared__ ushort Bs[128 * 32];

    const int tid  = threadIdx.x;
    const int wave = tid >> 6;
    const int lane = tid & 63;
    const int l32  = lane & 31;
    const int half = lane >> 5;
    const int bz = blockIdx.z;
    const int m0 = blockIdx.x * 128;
    const int n0 = blockIdx.y * 128;
    const int wm = (wave & 1) * 64;
    const int wn = (wave >> 1) * 64;
    const size_t base = (size_t)bz * SEQ;

    frag_c16 acc[2][2] = {};
    gemm_tiles(q + (base + m0) * DIM, DIM, kk + (base + n0) * DIM, DIM, DIM,
               As, Bs, acc);

    #pragma unroll
    for (int mi = 0; mi < 2; ++mi)
        #pragma unroll
        for (int r = 0; r < 16; ++r) {
            int row = m0 + wm + mi * 32 + (r & 3) + 8 * (r >> 2) + 4 * half;
            #pragma unroll
            for (int ni = 0; ni < 2; ++ni) {
                int col = n0 + wn + ni * 32 + l32;
                logits[(base + row) * SEQ + col] = acc[mi][ni][r];
            }
        }
}

// ---------------------------------------------------------------------------
// Kernel 4: row softmax over 2048 fp32, write bf16 probs in-place.
// ---------------------------------------------------------------------------
__global__ __launch_bounds__(256) void softmax_kernel(float* __restrict__ logits)
{
    float* p = logits + (size_t)blockIdx.x * SEQ;
    const int t = threadIdx.x;
    const int wave = t >> 6, lane = t & 63;

    float4 a = ((const float4*)p)[t];
    float4 b = ((const float4*)p)[t + 256];

    float m = fmaxf(fmaxf(fmaxf(a.x, a.y), fmaxf(a.z, a.w)),
                    fmaxf(fmaxf(b.x, b.y), fmaxf(b.z, b.w)));
    #pragma unroll
    for (int off = 32; off; off >>= 1) m = fmaxf(m, __shfl_down(m, off, 64));

    __shared__ float red[4];
    if (lane == 0) red[wave] = m;
    __syncthreads();
    m = fmaxf(fmaxf(red[0], red[1]), fmaxf(red[2], red[3]));

    a.x = __expf(a.x - m); a.y = __expf(a.y - m);
    a.z = __expf(a.z - m); a.w = __expf(a.w - m);
    b.x = __expf(b.x - m); b.y = __expf(b.y - m);
    b.z = __expf(b.z - m); b.w = __expf(b.w - m);

    float s = (a.x + a.y + a.z + a.w) + (b.x + b.y + b.z + b.w);
    #pragma unroll
    for (int off = 32; off; off >>= 1) s += __shfl_down(s, off, 64);
    __syncthreads();
    if (lane == 0) red[wave] = s;
    __syncthreads();
    s = red[0] + red[1] + red[2] + red[3];
    float inv = 1.0f / s;

    ushort* o = (ushort*)p;
    ushort4 u0, u1;
    u0.x = f2bf(a.x * inv); u0.y = f2bf(a.y * inv);
    u0.z = f2bf(a.z * inv); u0.w = f2bf(a.w * inv);
    u1.x = f2bf(b.x * inv); u1.y = f2bf(b.y * inv);
    u1.z = f2bf(b.z * inv); u1.w = f2bf(b.w * inv);
    ((ushort4*)o)[t]       = u0;
    ((ushort4*)o)[t + 256] = u1;
}

// ---------------------------------------------------------------------------
// Kernel 5: out = P vt^T (fp32). P rows stride 4096 ushorts. grid (16,8,4)
// ---------------------------------------------------------------------------
__global__ __launch_bounds__(256) void pv_kernel(
    const ushort* __restrict__ probs, const ushort* __restrict__ vt,
    float* __restrict__ out)
{
    __shared__ ushort As[128 * 32];
    __shared__ ushort Bs[128 * 32];

    const int tid  = threadIdx.x;
    const int wave = tid >> 6;
    const int lane = tid & 63;
    const int l32  = lane & 31;
    const int half = lane >> 5;
    const int bz = blockIdx.z;
    const int m0 = blockIdx.x * 128;
    const int n0 = blockIdx.y * 128;
    const int wm = (wave & 1) * 64;
    const int wn = (wave >> 1) * 64;

    frag_c16 acc[2][2] = {};
    gemm_tiles(probs + ((size_t)(bz * SEQ + m0)) * 4096, 4096,
               vt + ((size_t)(bz * DIM + n0)) * SEQ, SEQ, SEQ,
               As, Bs, acc);

    #pragma unroll
    for (int mi = 0; mi < 2; ++mi)
        #pragma unroll
        for (int r = 0; r < 16; ++r) {
            int row = m0 + wm + mi * 32 + (r & 3) + 8 * (r >> 2) + 4 * half;
            #pragma unroll
            for (int ni = 0; ni < 2; ++ni) {
                int col = n0 + wn + ni * 32 + l32;
                out[((size_t)(bz * SEQ + row)) * DIM + col] = acc[mi][ni][r];
            }
        }
}

// ---------------------------------------------------------------------------
extern "C" void kernel_launch(void* const* d_in, const int* in_sizes, int n_in,
                              void* d_out, int out_size, void* d_ws, size_t ws_size,
                              hipStream_t stream)
{
    const float* x  = (const float*)d_in[0];
    const float* Wq = (const float*)d_in[1];
    const float* bq = (const float*)d_in[2];
    const float* Wk = (const float*)d_in[3];
    const float* bk = (const float*)d_in[4];
    const float* Wv = (const float*)d_in[5];
    const float* bv = (const float*)d_in[6];
    float* out = (float*)d_out;

    char* ws = (char*)d_ws;
    ushort* q      = (ushort*)(ws);                           // 16 MB
    ushort* kk     = (ushort*)(ws + ((size_t)16 << 20));      // 16 MB
    ushort* v      = (ushort*)(ws + ((size_t)32 << 20));      // 16 MB
    ushort* vt     = (ushort*)(ws + ((size_t)48 << 20));      // 16 MB
    float*  logits = (float*) (ws + ((size_t)64 << 20));      // 64 MB
    ushort* xb     = (ushort*)(ws + ((size_t)64 << 20));      // aliases logits
    ushort* Wb     = (ushort*)(ws + ((size_t)80 << 20));      // aliases logits

    cvt_kernel<<<dim3((NX4 + 3 * NW4) / 256), 256, 0, stream>>>(
        x, Wq, Wk, Wv, xb, Wb);

    qkv_kernel<<<dim3(MTOT / 128, DIM / 128, 3), 256, 0, stream>>>(
        xb, Wb, bq, bk, bv, q, kk, v);
    transpose_v<<<dim3(SEQ / 64, DIM / 64, NB), 256, 0, stream>>>(v, vt);
    qk_kernel<<<dim3(SEQ / 128, SEQ / 128, NB), 256, 0, stream>>>(q, kk, logits);
    softmax_kernel<<<NB * SEQ, 256, 0, stream>>>(logits);
    pv_kernel<<<dim3(SEQ / 128, DIM / 128, NB), 256, 0, stream>>>(
        (const ushort*)logits, vt, out);
}